// Round 4
// baseline (1219.508 us; speedup 1.0000x reference)
//
#include <hip/hip_runtime.h>
#include <math.h>

#define BB 8192
#define TT 60
#define NU 100
#define NI 7

typedef float v2f __attribute__((ext_vector_type(2)));
typedef float v4f __attribute__((ext_vector_type(4)));

// ROUND 4: weight-distributed 4-wave block, 4 trials per block.
// Post-mortem of R0-R3: VGPR_Count 120-140 proves the "weights in 200 regs"
// idea NEVER happened — the compiler re-streamed W_rec from L1/L2 every
// step, every round. R3 exposed that latency at 1 wave/SIMD (VALUBusy 24%).
// Fix: wave w of each block holds a 28-wide k-chunk of its unit-pair rows
// (28 v2f = 56 VGPR, pinned via asm so it CANNOT be rematerialized), and
// each weight register is reused by 4 trials per step. Per step:
//   (A) all waves: partial dots, own k-chunk x 4 trials (112 pk_fma,
//       28 uniform ds_read_b128 of y-chunks)
//   (B) write 4 partials to LDS   (C) barrier
//   (D) wave w combines 4 chunk-partials for trial w, base+relu+update,
//       publishes y(t+1) to trial-w strip   (E) barrier
//   (F) wave w: z-tail (DPP reduce, sigmoid, lick state) + stores, own trial
// Symmetric: every wave owns exactly one trial's tail (no duplication —
// R2's mistake). 2 barriers/step, hidden by 3 waves/SIMD TLP.
// k-chunks are uniform 28 wide (k>=100 pads: zero weights, zeroed y pads).

#define KEEP(x) asm volatile("" : "+v"(x))
#define RL(v,l) __int_as_float(__builtin_amdgcn_readlane(__float_as_int(v), l))

#define DPPADD(ctrl, rmask) { \
  const int _t = __builtin_amdgcn_update_dpp(0, __float_as_int(part), (ctrl), (rmask), 0xf, false); \
  part += __int_as_float(_t); }

__global__ __launch_bounds__(256, 3)
void drr_kernel(const float* __restrict__ y0,
                const float* __restrict__ noise,
                const int*   __restrict__ stim_idx,
                const int*   __restrict__ rew_idx,
                const int*   __restrict__ instr_in,
                const float* __restrict__ W_in_raw,
                const float* __restrict__ W_rec,
                const float* __restrict__ b_rec,
                const float* __restrict__ w_out,
                const float* __restrict__ b_out,
                float* __restrict__ out)
{
    const int lane  = threadIdx.x & 63;
    const int wid   = threadIdx.x >> 6;        // k-chunk AND owned-trial slot
    const int trial = blockIdx.x * 4 + wid;    // this wave's OWN trial
    const int kc    = wid * 28;                // k-chunk start (uniform width)

    const bool act = (lane < 50);
    const int  la  = act ? lane : 49;
    const int  ua  = 2 * la;
    const int  uao = ua * NU;

    // own-trial scalars (wave-uniform -> SGPRs)
    const int  stim   = stim_idx[trial];
    const bool isrew  = (stim == rew_idx[trial]);
    const bool instrb = (instr_in[trial] > 0);

    // pinned weight chunk: 14 k-pairs of rows ua, ua+1 (56 VGPRs).
    // Pairs with k >= 100 are zero (pad); y pad slots are zeroed too.
    v2f wa[14], wb[14];
#pragma unroll
    for (int p = 0; p < 14; ++p) {
        const int k = kc + 2 * p;              // wave-uniform
        if (k < NU) {
            wa[p] = *(const v2f*)(W_rec + uao + k);
            wb[p] = *(const v2f*)(W_rec + uao + NU + k);
        } else {
            wa[p] = (v2f){0.0f, 0.0f};
            wb[p] = (v2f){0.0f, 0.0f};
        }
    }
#pragma unroll
    for (int p = 0; p < 14; ++p) { KEEP(wa[p]); KEEP(wb[p]); }

    // W_in columns (abs), own trial's stim column
    const v2f wi6 = { fabsf(W_in_raw[ua * NI + 6]),    fabsf(W_in_raw[(ua+1) * NI + 6]) };
    const v2f wis = { fabsf(W_in_raw[ua * NI + stim]), fabsf(W_in_raw[(ua+1) * NI + stim]) };
    const v2f wr  = { fabsf(W_in_raw[ua * NI + 4]),    fabsf(W_in_raw[(ua+1) * NI + 4]) };
    const v2f wl  = { fabsf(W_in_raw[ua * NI + 5]),    fabsf(W_in_raw[(ua+1) * NI + 5]) };
    const v2f br  = { b_rec[ua], b_rec[ua + 1] };
    const v2f wo  = act ? (v2f){ w_out[ua], w_out[ua + 1] } : (v2f){ 0.0f, 0.0f };
    const float bo = b_out[0];

    v2f yy = ((const v2f*)(y0 + trial * NU))[la];

    const float NS = 0.09486832980505138f;     // 0.15 * sqrt(2*0.2)

    bool licked = false, fired = false;
    int  lickt = TT + 1;

    const float* nbase = noise + trial * (TT * NU);
    v2f en = ((const v2f*)nbase)[la];          // t=0 prefetch

    // y strips: [trial][28 v4f] = 112 floats (slots 100..111 are zero pads)
    __shared__ v4f lds_y[4][28];
    // chunk-partials: [trial][chunk][lane] v2f, lane-stride 8B (conflict-free)
    __shared__ v2f lds_p[4][4][64];

    // init: publish y0 and zero the pad slots (v2f slots 50..55)
    if (lane < 56)
        ((v2f*)&lds_y[wid][0])[lane] = act ? yy : (v2f){0.0f, 0.0f};
    __syncthreads();

    // output section pointers (flat tuple order)
    float* uout  = out;                        // B*T*7
    float* tout  = out  + BB * TT * NI;        // B*T
    float* rout  = tout + BB * TT;             // B*T
    float* lout  = rout + BB * TT;             // B
    float* dout  = lout + BB;                  // B
    float* zout  = dout + BB;                  // B*T
    float* yfout = zout + BB * TT;             // B*100

    const v4f* Y0 = (const v4f*)&lds_y[0][0] + (kc >> 2);
    const v4f* Y1 = (const v4f*)&lds_y[1][0] + (kc >> 2);
    const v4f* Y2 = (const v4f*)&lds_y[2][0] + (kc >> 2);
    const v4f* Y3 = (const v4f*)&lds_y[3][0] + (kc >> 2);

    for (int t = 0; t < TT; ++t) {
        // ---- (A) partial dots: own k-chunk, all 4 trials ----
        v2f a0A = {0,0}, a0B = {0,0}, a1A = {0,0}, a1B = {0,0};
        v2f a2A = {0,0}, a2B = {0,0}, a3A = {0,0}, a3B = {0,0};
#pragma unroll
        for (int g = 0; g < 7; ++g) {
            const v4f q0 = Y0[g];
            const v4f q1 = Y1[g];
            const v4f q2 = Y2[g];
            const v4f q3 = Y3[g];
            const v2f wA0 = wa[2*g], wA1 = wa[2*g+1];
            const v2f wB0 = wb[2*g], wB1 = wb[2*g+1];
            a0A += (v2f){q0.x,q0.y} * wA0;  a0A += (v2f){q0.z,q0.w} * wA1;
            a0B += (v2f){q0.x,q0.y} * wB0;  a0B += (v2f){q0.z,q0.w} * wB1;
            a1A += (v2f){q1.x,q1.y} * wA0;  a1A += (v2f){q1.z,q1.w} * wA1;
            a1B += (v2f){q1.x,q1.y} * wB0;  a1B += (v2f){q1.z,q1.w} * wB1;
            a2A += (v2f){q2.x,q2.y} * wA0;  a2A += (v2f){q2.z,q2.w} * wA1;
            a2B += (v2f){q2.x,q2.y} * wB0;  a2B += (v2f){q2.z,q2.w} * wB1;
            a3A += (v2f){q3.x,q3.y} * wA0;  a3A += (v2f){q3.z,q3.w} * wA1;
            a3B += (v2f){q3.x,q3.y} * wB0;  a3B += (v2f){q3.z,q3.w} * wB1;
        }

        // ---- (B) write chunk-partials (horizontal-summed, unit-packed) ----
        if (act) {
            lds_p[0][wid][lane] = (v2f){ a0A.x + a0A.y, a0B.x + a0B.y };
            lds_p[1][wid][lane] = (v2f){ a1A.x + a1A.y, a1B.x + a1B.y };
            lds_p[2][wid][lane] = (v2f){ a2A.x + a2A.y, a2B.x + a2B.y };
            lds_p[3][wid][lane] = (v2f){ a3A.x + a3A.y, a3B.x + a3B.y };
        }
        __syncthreads();                       // bar1: partials visible

        // ---- (D) own trial: combine, route, update, publish ----
        const v2f e = en;
        const int tn = (t < TT - 1) ? t + 1 : t;
        en = ((const v2f*)(nbase + tn * NU))[la];

        const float sm = (t >= 10 && t < 15) ? 1.0f : 0.0f;
        const float rm = (t >= 20 && t < 35) ? 1.0f : 0.0f;

        const bool dl = fired || (licked && isrew);
        const bool fr = instrb && !dl && (t == 30);
        fired = fired || fr;
        const bool ia = fired && (t >= 30) && (t < 35);
        const bool ld = licked && (t > lickt) && (t < lickt + 5);
        const float ar = (ia ? 1.0f : 0.0f) + ((ld && isrew) ? 1.0f : 0.0f);
        const float al = ld ? 1.0f : 0.0f;
        const v2f base = br + rm * wi6 + sm * wis + ar * wr + al * wl + NS * e;

        const v2f psum = lds_p[wid][0][la] + lds_p[wid][1][la]
                       + lds_p[wid][2][la] + lds_p[wid][3][la];
        const v2f pre  = base + psum;
        const v2f prer = { fmaxf(pre.x, 0.0f), fmaxf(pre.y, 0.0f) };
        yy = 0.8f * yy + 0.2f * prer;

        if (act)
            ((v2f*)&lds_y[wid][0])[lane] = yy; // publish y(t+1), pads stay 0
        __syncthreads();                       // bar2: y strips visible

        // ---- (F) own trial tail: z, lick state, stores ----
        float part = yy.x * wo.x + yy.y * wo.y;
        DPPADD(0x111, 0xf)   // row_shr:1
        DPPADD(0x112, 0xf)   // row_shr:2
        DPPADD(0x114, 0xf)   // row_shr:4
        DPPADD(0x118, 0xf)   // row_shr:8
        DPPADD(0x142, 0xa)   // row_bcast:15 -> rows 1,3
        DPPADD(0x143, 0xc)   // row_bcast:31 -> rows 2,3
        const float xx = RL(part, 63) + bo;
        const float z  = 1.0f / (1.0f + expf(-xx));

        const bool inr  = (t >= 20) && (t < 35);
        const bool trig = inr && !licked && (z > 0.5f);
        if (trig) lickt = t;                   // wave-uniform
        licked = licked || trig;
        const bool u5 = licked && (t >= lickt) && (t < lickt + 5);
        const bool u4 = ia || (u5 && isrew);

        const int bt = trial * TT + t;
        if (lane < NI) {
            float uv = 0.0f;
            if (lane == stim) uv = sm;
            if (lane == 4)    uv = u4 ? 1.0f : 0.0f;
            if (lane == 5)    uv = u5 ? 1.0f : 0.0f;
            if (lane == 6)    uv = rm;
            uout[bt * NI + lane] = uv;
        } else if (lane == 8) {
            tout[bt] = isrew ? rm : 0.0f;
        } else if (lane == 9) {
            rout[bt] = rm;
        } else if (lane == 10) {
            zout[bt] = z;
        }
    }

    if (lane == 0) {
        lout[trial] = licked ? 1.0f : 0.0f;
        dout[trial] = (fired || (licked && isrew)) ? 1.0f : 0.0f;
    }
    if (act)
        ((v2f*)(yfout + trial * NU))[la] = yy;
}

extern "C" void kernel_launch(void* const* d_in, const int* in_sizes, int n_in,
                              void* d_out, int out_size, void* d_ws, size_t ws_size,
                              hipStream_t stream) {
    const float* y0       = (const float*)d_in[0];
    const float* noise    = (const float*)d_in[1];
    const int*   stim     = (const int*)  d_in[2];
    const int*   rew      = (const int*)  d_in[3];
    const int*   instr    = (const int*)  d_in[4];
    const float* W_in_raw = (const float*)d_in[5];
    const float* W_rec    = (const float*)d_in[6];
    const float* b_rec    = (const float*)d_in[7];
    const float* w_out    = (const float*)d_in[8];
    const float* b_out    = (const float*)d_in[9];
    float* out = (float*)d_out;

    drr_kernel<<<BB / 4, 256, 0, stream>>>(y0, noise, stim, rew, instr,
                                           W_in_raw, W_rec, b_rec, w_out, b_out, out);
}

// Round 5
// 508.389 us; speedup vs baseline: 2.3988x; 2.3988x over previous
//
#include <hip/hip_runtime.h>
#include <math.h>

#define BB 8192
#define TT 60
#define NU 100
#define NI 7

typedef float v2f __attribute__((ext_vector_type(2)));
typedef float v4f __attribute__((ext_vector_type(4)));

// ROUND 5: weights in LDS, 4 trials per wave, barrier-free main loop.
// R0-R4 lesson: the compiler will NOT keep a 200-reg weight set in VGPRs —
// it re-streams from L1/L2 (R0-R3, VGPR 120-140) or scratch-spills when
// asm-pinned (R4: WRITE_SIZE 3.66 GB). So weights live in LDS (40 KB,
// staged once per block, shared by 4 waves), and each LDS weight read is
// amortized over 4 trials handled by the same wave.
// Layout: wtX[j*50+l] = {W[2l][2j], W[2l][2j+1]} (even unit of lane l),
//         wtY[j*50+l] = same for odd unit 2l+1. Lane-stride 8 B -> <=2-way.
// Per step per wave: 4 ds_write_b64 (publish y), 25 x {4 weight b64 +
// 4 uniform y b128 + 16 pk_fma}, 4 independent tails. No barriers in loop.
// The per-iteration asm launder of `wofs` makes weight addresses
// loop-variant so LICM can't hoist the 100 LDS reads into registers.

#define FOR25(M) M(0) M(1) M(2) M(3) M(4) M(5) M(6) M(7) M(8) M(9) \
  M(10) M(11) M(12) M(13) M(14) M(15) M(16) M(17) M(18) M(19) \
  M(20) M(21) M(22) M(23) M(24)

#define RL(v,l) __int_as_float(__builtin_amdgcn_readlane(__float_as_int(v), l))

#define DPPADD(ctrl, rmask) { \
  const int _t = __builtin_amdgcn_update_dpp(0, __float_as_int(part), (ctrl), (rmask), 0xf, false); \
  part += __int_as_float(_t); }

#define TRIAL_SETUP(s) \
  const int  trial##s  = tbase + s; \
  const int  stim##s   = stim_idx[trial##s]; \
  const bool isrew##s  = (stim##s == rew_idx[trial##s]); \
  const bool instrb##s = (instr_in[trial##s] > 0); \
  const v2f  wis##s = { fabsf(W_in_raw[ua * NI + stim##s]), fabsf(W_in_raw[(ua+1) * NI + stim##s]) }; \
  v2f  yy##s = ((const v2f*)(y0 + trial##s * NU))[la]; \
  bool licked##s = false, fired##s = false; \
  int  lickt##s = TT + 1; \
  const float* nbase##s = noise + trial##s * (TT * NU); \
  v2f  en##s = ((const v2f*)nbase##s)[la];

#define PUBLISH(s) ((v2f*)&lds_y[wid * 4 + s][0])[la] = yy##s;

#define DECLACC(s) v2f aX0_##s = {0,0}, aX1_##s = {0,0}, aY0_##s = {0,0}, aY1_##s = {0,0};

#define MACQ(s, j2) { \
  const v4f q = Y##s[j2]; \
  aX0_##s += (v2f){q.x, q.y} * wx0; \
  aY0_##s += (v2f){q.x, q.y} * wy0; \
  aX1_##s += (v2f){q.z, q.w} * wx1; \
  aY1_##s += (v2f){q.z, q.w} * wy1; }

// one group: k = 4*j2 .. 4*j2+3; 4 weight b64 shared by all 4 trials
#define MACJ2(j2) { \
  const v2f wx0 = wX[(2*(j2)    ) * 50 + la]; \
  const v2f wx1 = wX[(2*(j2) + 1) * 50 + la]; \
  const v2f wy0 = wY[(2*(j2)    ) * 50 + la]; \
  const v2f wy1 = wY[(2*(j2) + 1) * 50 + la]; \
  MACQ(0, j2) MACQ(1, j2) MACQ(2, j2) MACQ(3, j2) }

// route + base + combine + leaky-relu update for trial s at step t
#define TAILA(s, t, sm, rm) { \
  const v2f e = en##s; \
  en##s = ((const v2f*)(nbase##s + tn * NU))[la]; \
  const bool dl = fired##s || (licked##s && isrew##s); \
  const bool fr = instrb##s && !dl && ((t) == 30); \
  fired##s = fired##s || fr; \
  ia##s = fired##s && ((t) >= 30) && ((t) < 35); \
  const bool ld = licked##s && ((t) > lickt##s) && ((t) < lickt##s + 5); \
  const float ar = (ia##s ? 1.0f : 0.0f) + ((ld && isrew##s) ? 1.0f : 0.0f); \
  const float al = ld ? 1.0f : 0.0f; \
  const v2f base = br + (rm) * wi6 + (sm) * wis##s + ar * wr + al * wl + NS * e; \
  const v2f sX = aX0_##s + aX1_##s; \
  const v2f sY = aY0_##s + aY1_##s; \
  const v2f pre  = base + (v2f){ sX.x + sX.y, sY.x + sY.y }; \
  const v2f prer = { fmaxf(pre.x, 0.0f), fmaxf(pre.y, 0.0f) }; \
  yy##s = 0.8f * yy##s + 0.2f * prer; }

// z-reduction + lick state for trial s at step t
#define ZED(s, t) { \
  float part = yy##s.x * wo.x + yy##s.y * wo.y; \
  DPPADD(0x111, 0xf) DPPADD(0x112, 0xf) DPPADD(0x114, 0xf) DPPADD(0x118, 0xf) \
  DPPADD(0x142, 0xa) DPPADD(0x143, 0xc) \
  const float xx = RL(part, 63) + bo; \
  z##s = 1.0f / (1.0f + expf(-xx)); \
  const bool inr  = ((t) >= 20) && ((t) < 35); \
  const bool trig = inr && !licked##s && (z##s > 0.5f); \
  if (trig) lickt##s = (t); \
  licked##s = licked##s || trig; \
  u5##s = licked##s && ((t) >= lickt##s) && ((t) < lickt##s + 5); \
  u4##s = ia##s || (u5##s && isrew##s); }

#define FSTORE(s, t, sm, rm) { \
  const int bt = trial##s * TT + (t); \
  if (lane < NI) { \
    float uv = 0.0f; \
    if (lane == stim##s) uv = (sm); \
    if (lane == 4) uv = u4##s ? 1.0f : 0.0f; \
    if (lane == 5) uv = u5##s ? 1.0f : 0.0f; \
    if (lane == 6) uv = (rm); \
    uout[bt * NI + lane] = uv; \
  } else if (lane == 8) { tout[bt] = isrew##s ? (rm) : 0.0f; } \
  else if (lane == 9)   { rout[bt] = (rm); } \
  else if (lane == 10)  { zout[bt] = z##s; } }

__global__ __launch_bounds__(256, 2)
void drr_kernel(const float* __restrict__ y0,
                const float* __restrict__ noise,
                const int*   __restrict__ stim_idx,
                const int*   __restrict__ rew_idx,
                const int*   __restrict__ instr_in,
                const float* __restrict__ W_in_raw,
                const float* __restrict__ W_rec,
                const float* __restrict__ b_rec,
                const float* __restrict__ w_out,
                const float* __restrict__ b_out,
                float* __restrict__ out)
{
    const int tid   = threadIdx.x;
    const int lane  = tid & 63;
    const int wid   = tid >> 6;
    const int tbase = blockIdx.x * 16 + wid * 4;   // 4 trials per wave

    const bool act = (lane < 50);
    const int  la  = act ? lane : 49;
    const int  ua  = 2 * la;

    // transposed-pair weight tiles (40 KB) + per-trial y strips (6.5 KB)
    __shared__ v2f wtX[2500];        // [j][l] = {W[2l][2j],   W[2l][2j+1]}
    __shared__ v2f wtY[2500];        // [j][l] = {W[2l+1][2j], W[2l+1][2j+1]}
    __shared__ v4f lds_y[16][26];    // strip per (wave,trial); 25 v4f used

    // stage weights once per block (writes lane-stride 8B: conflict-free)
    for (int idx = tid; idx < 2500; idx += 256) {
        const int j = idx / 50, l = idx % 50;
        wtX[idx] = *(const v2f*)(W_rec + (2 * l)     * NU + 2 * j);
        wtY[idx] = *(const v2f*)(W_rec + (2 * l + 1) * NU + 2 * j);
    }
    __syncthreads();                 // only barrier in the kernel

    // shared per-unit parameters
    const v2f wi6 = { fabsf(W_in_raw[ua * NI + 6]), fabsf(W_in_raw[(ua+1) * NI + 6]) };
    const v2f wr  = { fabsf(W_in_raw[ua * NI + 4]), fabsf(W_in_raw[(ua+1) * NI + 4]) };
    const v2f wl  = { fabsf(W_in_raw[ua * NI + 5]), fabsf(W_in_raw[(ua+1) * NI + 5]) };
    const v2f br  = { b_rec[ua], b_rec[ua + 1] };
    const v2f wo  = act ? (v2f){ w_out[ua], w_out[ua + 1] } : (v2f){ 0.0f, 0.0f };
    const float bo = b_out[0];
    const float NS = 0.09486832980505138f;   // 0.15 * sqrt(2*0.2)

    TRIAL_SETUP(0) TRIAL_SETUP(1) TRIAL_SETUP(2) TRIAL_SETUP(3)

    const v4f* Y0 = &lds_y[wid * 4 + 0][0];
    const v4f* Y1 = &lds_y[wid * 4 + 1][0];
    const v4f* Y2 = &lds_y[wid * 4 + 2][0];
    const v4f* Y3 = &lds_y[wid * 4 + 3][0];

    // output section pointers (flat tuple order)
    float* uout  = out;                        // B*T*7
    float* tout  = out  + BB * TT * NI;        // B*T
    float* rout  = tout + BB * TT;             // B*T
    float* lout  = rout + BB * TT;             // B
    float* dout  = lout + BB;                  // B
    float* zout  = dout + BB;                  // B*T
    float* yfout = zout + BB * TT;             // B*100

    for (int t = 0; t < TT; ++t) {
        // opaque zero offset, refreshed per iteration: weight addresses are
        // loop-variant -> LICM cannot hoist the 100 ds_reads into registers
        unsigned wofs = 0;
        asm volatile("" : "+v"(wofs));
        const v2f* wX = (const v2f*)wtX + wofs;
        const v2f* wY = (const v2f*)wtY + wofs;

        // publish current y (wave-local DS ordering; no barrier needed)
        PUBLISH(0) PUBLISH(1) PUBLISH(2) PUBLISH(3)

        DECLACC(0) DECLACC(1) DECLACC(2) DECLACC(3)

        FOR25(MACJ2)     // 100 weight b64 + 100 uniform y b128 + 400 pk_fma

        const int tn = (t < TT - 1) ? t + 1 : t;
        const float sm = (t >= 10 && t < 15) ? 1.0f : 0.0f;
        const float rm = (t >= 20 && t < 35) ? 1.0f : 0.0f;

        bool ia0, ia1, ia2, ia3;
        float z0, z1, z2, z3;
        bool u40, u41, u42, u43, u50, u51, u52, u53;

        TAILA(0, t, sm, rm) TAILA(1, t, sm, rm)
        TAILA(2, t, sm, rm) TAILA(3, t, sm, rm)

        ZED(0, t) ZED(1, t) ZED(2, t) ZED(3, t)

        FSTORE(0, t, sm, rm) FSTORE(1, t, sm, rm)
        FSTORE(2, t, sm, rm) FSTORE(3, t, sm, rm)
    }

    if (lane == 0) {
        lout[trial0] = licked0 ? 1.0f : 0.0f;
        dout[trial0] = (fired0 || (licked0 && isrew0)) ? 1.0f : 0.0f;
        lout[trial1] = licked1 ? 1.0f : 0.0f;
        dout[trial1] = (fired1 || (licked1 && isrew1)) ? 1.0f : 0.0f;
        lout[trial2] = licked2 ? 1.0f : 0.0f;
        dout[trial2] = (fired2 || (licked2 && isrew2)) ? 1.0f : 0.0f;
        lout[trial3] = licked3 ? 1.0f : 0.0f;
        dout[trial3] = (fired3 || (licked3 && isrew3)) ? 1.0f : 0.0f;
    }
    if (act) {
        ((v2f*)(yfout + trial0 * NU))[la] = yy0;
        ((v2f*)(yfout + trial1 * NU))[la] = yy1;
        ((v2f*)(yfout + trial2 * NU))[la] = yy2;
        ((v2f*)(yfout + trial3 * NU))[la] = yy3;
    }
}

extern "C" void kernel_launch(void* const* d_in, const int* in_sizes, int n_in,
                              void* d_out, int out_size, void* d_ws, size_t ws_size,
                              hipStream_t stream) {
    const float* y0       = (const float*)d_in[0];
    const float* noise    = (const float*)d_in[1];
    const int*   stim     = (const int*)  d_in[2];
    const int*   rew      = (const int*)  d_in[3];
    const int*   instr    = (const int*)  d_in[4];
    const float* W_in_raw = (const float*)d_in[5];
    const float* W_rec    = (const float*)d_in[6];
    const float* b_rec    = (const float*)d_in[7];
    const float* w_out    = (const float*)d_in[8];
    const float* b_out    = (const float*)d_in[9];
    float* out = (float*)d_out;

    drr_kernel<<<BB / 16, 256, 0, stream>>>(y0, noise, stim, rew, instr,
                                            W_in_raw, W_rec, b_rec, w_out, b_out, out);
}